// Round 4
// baseline (442.655 us; speedup 1.0000x reference)
//
#include <hip/hip_runtime.h>
#include <math.h>

// Problem constants (from reference)
#define B_  64
#define S_  2048
#define E_  300
#define H_  150
#define C_  34
#define CHUNK 128
#define NCHUNK (S_ / CHUNK)   // 16
#define WAVES 4               // 256-thread blocks

// ---------------------------------------------------------------------------
// Attention chunk pass — VERBATIM round-0 inner loop (proven 169.9 µs shape;
// round-2/3 taught us: do NOT hand-pipeline this, the compiler's full unroll
// already schedules it within 64 VGPRs; explicit ping-pong was -9 µs/pass,
// full hoist was 235 MB of scratch spill).
// Writes per-chunk (m, l, unnormalized h[300]) partials.
// ---------------------------------------------------------------------------
__device__ __forceinline__ void attn_chunk(
    const int* __restrict__ x, const float* __restrict__ emb,
    const float* __restrict__ qmat, int q_stride, float scale,
    float* __restrict__ h_part, float* __restrict__ m_part,
    float* __restrict__ l_part, int b, int chunk, int tid)
{
    const int w    = tid >> 6;
    const int lane = tid & 63;

    const float4* qp = (const float4*)(qmat + (size_t)b * q_stride);
    float4 q0 = qp[lane];
    float4 q1 = make_float4(0.f, 0.f, 0.f, 0.f);
    if (lane < 11) q1 = qp[64 + lane];
    q0.x *= scale; q0.y *= scale; q0.z *= scale; q0.w *= scale;
    q1.x *= scale; q1.y *= scale; q1.z *= scale; q1.w *= scale;

    const int base = b * S_ + chunk * CHUNK;
    int myidx = 0;
    if (lane < 32) myidx = x[base + w + 4 * lane];

    float  m = -INFINITY, l = 0.f;
    float4 a0 = make_float4(0.f, 0.f, 0.f, 0.f);
    float4 a1 = make_float4(0.f, 0.f, 0.f, 0.f);

    for (int g = 0; g < 8; ++g) {
        float4 r0[4], r1[4];
        #pragma unroll
        for (int t = 0; t < 4; ++t) {
            const int row = __shfl(myidx, 4 * g + t);
            const float4* rp = (const float4*)(emb + (size_t)row * E_);
            r0[t] = rp[lane];
            r1[t] = make_float4(0.f, 0.f, 0.f, 0.f);
            if (lane < 11) r1[t] = rp[64 + lane];
        }
        float d[4];
        #pragma unroll
        for (int t = 0; t < 4; ++t)
            d[t] = q0.x * r0[t].x + q0.y * r0[t].y + q0.z * r0[t].z + q0.w * r0[t].w
                 + q1.x * r1[t].x + q1.y * r1[t].y + q1.z * r1[t].z + q1.w * r1[t].w;
        #pragma unroll
        for (int off = 32; off > 0; off >>= 1) {
            #pragma unroll
            for (int t = 0; t < 4; ++t) d[t] += __shfl_xor(d[t], off);
        }
        const float gm = fmaxf(fmaxf(d[0], d[1]), fmaxf(d[2], d[3]));
        const float mn = fmaxf(m, gm);
        const float c  = __expf(m - mn);
        const float p0 = __expf(d[0] - mn), p1 = __expf(d[1] - mn);
        const float p2 = __expf(d[2] - mn), p3 = __expf(d[3] - mn);
        l = l * c + ((p0 + p1) + (p2 + p3));
        a0.x = a0.x * c + p0 * r0[0].x + p1 * r0[1].x + p2 * r0[2].x + p3 * r0[3].x;
        a0.y = a0.y * c + p0 * r0[0].y + p1 * r0[1].y + p2 * r0[2].y + p3 * r0[3].y;
        a0.z = a0.z * c + p0 * r0[0].z + p1 * r0[1].z + p2 * r0[2].z + p3 * r0[3].z;
        a0.w = a0.w * c + p0 * r0[0].w + p1 * r0[1].w + p2 * r0[2].w + p3 * r0[3].w;
        a1.x = a1.x * c + p0 * r1[0].x + p1 * r1[1].x + p2 * r1[2].x + p3 * r1[3].x;
        a1.y = a1.y * c + p0 * r1[0].y + p1 * r1[1].y + p2 * r1[2].y + p3 * r1[3].y;
        a1.z = a1.z * c + p0 * r1[0].z + p1 * r1[1].z + p2 * r1[2].z + p3 * r1[3].z;
        a1.w = a1.w * c + p0 * r1[0].w + p1 * r1[1].w + p2 * r1[2].w + p3 * r1[3].w;
        m = mn;
    }

    __shared__ float sm[WAVES], sl[WAVES];
    __shared__ __align__(16) float sacc[WAVES][304];
    ((float4*)sacc[w])[lane] = a0;
    if (lane < 11) ((float4*)sacc[w])[64 + lane] = a1;
    if (lane == 0) { sm[w] = m; sl[w] = l; }
    __syncthreads();

    const float mb = fmaxf(fmaxf(sm[0], sm[1]), fmaxf(sm[2], sm[3]));
    const int pi = b * NCHUNK + chunk;
    for (int j = tid; j < E_; j += 256) {
        float h = 0.f;
        #pragma unroll
        for (int c = 0; c < WAVES; ++c)
            h += __expf(sm[c] - mb) * sacc[c][j];
        h_part[(size_t)pi * E_ + j] = h;
    }
    if (tid == 0) {
        float lb = 0.f;
        #pragma unroll
        for (int c = 0; c < WAVES; ++c) lb += __expf(sm[c] - mb) * sl[c];
        m_part[pi] = mb; l_part[pi] = lb;
    }
}

// Block-wide fan-in: returns true for exactly the LAST block (of NCHUNK) to
// finish for this b, with all other blocks' partial writes visible.
__device__ __forceinline__ bool fanin_last(int* cnt, int b, int tid)
{
    __shared__ int lastFlag;
    __threadfence();                       // release partial writes
    if (tid == 0)
        lastFlag = (atomicAdd(&cnt[b], 1) == NCHUNK - 1);
    __syncthreads();
    if (!lastFlag) return false;
    __threadfence();                       // acquire other blocks' writes
    return true;
}

// ---------------------------------------------------------------------------
// Pass 1: attention + (last block per b) combine -> h1, v2 = (h1@W)@W^T
// ---------------------------------------------------------------------------
__global__ __launch_bounds__(256, 4) void attn1_qv(
    const int* __restrict__ x, const float* __restrict__ emb,
    const float* __restrict__ query, const float* __restrict__ W,
    float* __restrict__ h_part, float* __restrict__ m_part,
    float* __restrict__ l_part, float* __restrict__ h1,
    float* __restrict__ v2, int* __restrict__ cnt)
{
    const int b = blockIdx.y, chunk = blockIdx.x, tid = threadIdx.x;
    const float scale1 = 0.05773502691896258f;   // 1/sqrt(300)

    attn_chunk(x, emb, query, 0, scale1, h_part, m_part, l_part, b, chunk, tid);

    if (!fanin_last(cnt, b, tid)) return;

    // ---- combine (order-identical to proven combine_qv, 256 threads) ----
    __shared__ float smc[NCHUNK], slc[NCHUNK], sh[E_], sq[H_];
    if (tid < NCHUNK) { smc[tid] = m_part[b * NCHUNK + tid];
                        slc[tid] = l_part[b * NCHUNK + tid]; }
    __syncthreads();
    float M = -INFINITY;
    #pragma unroll
    for (int c = 0; c < NCHUNK; ++c) M = fmaxf(M, smc[c]);
    float L = 0.f;
    #pragma unroll
    for (int c = 0; c < NCHUNK; ++c) L += __expf(smc[c] - M) * slc[c];
    for (int j = tid; j < E_; j += 256) {
        float h = 0.f;
        #pragma unroll
        for (int c = 0; c < NCHUNK; ++c)
            h += __expf(smc[c] - M) * h_part[((size_t)b * NCHUNK + c) * E_ + j];
        const float v = h / L;
        sh[j] = v;
        h1[b * E_ + j] = v;
    }
    __syncthreads();
    if (tid < H_) {
        float acc = 0.f;
        for (int e = 0; e < E_; ++e) acc += sh[e] * W[e * H_ + tid];
        sq[tid] = acc;
    }
    __syncthreads();
    for (int j = tid; j < E_; j += 256) {
        float acc = 0.f;
        const float* wr = W + (size_t)j * H_;
        for (int h = 0; h < H_; ++h) acc += sq[h] * wr[h];
        v2[b * E_ + j] = acc;
    }
}

// ---------------------------------------------------------------------------
// Pass 2: attention (query v2) + (last block per b) combine -> scores
// ---------------------------------------------------------------------------
__global__ __launch_bounds__(256, 4) void attn2_scores(
    const int* __restrict__ x, const float* __restrict__ emb,
    const float* __restrict__ v2, const float* __restrict__ h1,
    const float* __restrict__ Wout, const float* __restrict__ bias,
    float* __restrict__ h_part, float* __restrict__ m_part,
    float* __restrict__ l_part, float* __restrict__ out,
    int* __restrict__ cnt)
{
    const int b = blockIdx.y, chunk = blockIdx.x, tid = threadIdx.x;

    attn_chunk(x, emb, v2, E_, 1.0f, h_part, m_part, l_part, b, chunk, tid);

    if (!fanin_last(cnt, b, tid)) return;

    // ---- combine (order-identical to proven combine_scores, 256 threads) ----
    __shared__ float smc[NCHUNK], slc[NCHUNK];
    __shared__ float hh[2 * E_];
    if (tid < NCHUNK) { smc[tid] = m_part[b * NCHUNK + tid];
                        slc[tid] = l_part[b * NCHUNK + tid]; }
    for (int j = tid; j < E_; j += 256) hh[j] = h1[b * E_ + j];
    __syncthreads();
    float M = -INFINITY;
    #pragma unroll
    for (int c = 0; c < NCHUNK; ++c) M = fmaxf(M, smc[c]);
    float L = 0.f;
    #pragma unroll
    for (int c = 0; c < NCHUNK; ++c) L += __expf(smc[c] - M) * slc[c];
    for (int j = tid; j < E_; j += 256) {
        float h = 0.f;
        #pragma unroll
        for (int c = 0; c < NCHUNK; ++c)
            h += __expf(smc[c] - M) * h_part[((size_t)b * NCHUNK + c) * E_ + j];
        hh[E_ + j] = h / L;
    }
    __syncthreads();
    const int w = tid >> 6, lane = tid & 63;
    for (int c = w; c < C_; c += 4) {     // 4 waves cover 34 classes
        float p = 0.f;
        for (int e = lane; e < 2 * E_; e += 64)
            p += hh[e] * Wout[(size_t)e * C_ + c];
        #pragma unroll
        for (int off = 32; off > 0; off >>= 1) p += __shfl_xor(p, off);
        if (lane == 0) out[b * C_ + c] = p + bias[c];
    }
}

extern "C" void kernel_launch(void* const* d_in, const int* in_sizes, int n_in,
                              void* d_out, int out_size, void* d_ws, size_t ws_size,
                              hipStream_t stream) {
    const int*   x     = (const int*)  d_in[0];   // [64,2048] int32
    const float* emb   = (const float*)d_in[1];   // [50000,300]
    const float* query = (const float*)d_in[2];   // [1,300]
    const float* Watt  = (const float*)d_in[3];   // [300,150]
    const float* Wout  = (const float*)d_in[4];   // [600,34]
    const float* bias  = (const float*)d_in[5];   // [34]
    float* out = (float*)d_out;                   // [64,34]

    // Workspace layout (floats)
    float* ws     = (float*)d_ws;
    float* h_part = ws;                                 // B*NCHUNK*E = 307200
    float* m_part = h_part + (size_t)B_ * NCHUNK * E_;  // 1024
    float* l_part = m_part + B_ * NCHUNK;               // 1024
    float* h1     = l_part + B_ * NCHUNK;               // 19200
    float* v2     = h1 + B_ * E_;                       // 19200
    int*   cnt1   = (int*)(v2 + B_ * E_);               // 64
    int*   cnt2   = cnt1 + B_;                          // 64

    // Zero fan-in counters (workspace is poisoned between iterations)
    hipMemsetAsync(cnt1, 0, 2 * B_ * sizeof(int), stream);

    dim3 grid(NCHUNK, B_), blk(256);
    attn1_qv<<<grid, blk, 0, stream>>>(x, emb, query, Watt,
                                       h_part, m_part, l_part, h1, v2, cnt1);
    attn2_scores<<<grid, blk, 0, stream>>>(x, emb, v2, h1, Wout, bias,
                                           h_part, m_part, l_part, out, cnt2);
}